// Round 12
// baseline (189.630 us; speedup 1.0000x reference)
//
#include <hip/hip_runtime.h>

// MHA forward. Inputs/output f32; internal bf16 MFMA pipeline.
// b=2, s=2048, d_model=1024, heads=16, head_dim=64.
// cvt (f32->bf16) -> fused QKV gemm128s (128x128x64, As/Bs XOR-swizzled
// fragment path (R11, 9.6M->~0 conflict cy); R12: XCD-aware block swizzle,
// col-major decode -> 3 B-panels resident per XCD L2) ->
// attn15b (K shared via LDS w/ XOR swizzle + async gld dbuf; V reg-prefetch
// -> SINGLE padded LDS buffer w/ 2 barriers/tile (R12): 67.6KB -> 49KB LDS
// -> 3 blocks/CU = 12 waves (R11 was latency-bound at 8 waves/CU);
// static-max softmax; longest-first dispatch) ->
// gemm64s (swizzled; XCD block swizzle; O x Wo^T -> f32).
// HISTORY: attn8/attn10/attn14 spilled when register demand rose -> ONE unit
// instantiation, ONE accumulator bank, NO min-wave launch_bounds. attn13:
// per-lane V gather from L2 = 3x regression (K/V must be LDS-shared).
// attn9/12: occupancy/balance levers exhausted; only BYTES+CONFLICTS+WAVES.
// V cannot use global_load_lds: any 16B-granule swizzle either collides with
// the jt read bits or degrades to 4-way -- padded reg-staged V is optimal.

typedef __bf16 bf16_t;
typedef __attribute__((ext_vector_type(8))) __bf16 bf16x8;
typedef __attribute__((ext_vector_type(4))) __bf16 bf16x4;
typedef __attribute__((ext_vector_type(4))) short s16x4;
typedef __attribute__((ext_vector_type(4))) float f32x4;

#define MFMA16 __builtin_amdgcn_mfma_f32_16x16x32_bf16
#define MFMA16K16 __builtin_amdgcn_mfma_f32_16x16x16bf16_1k

__device__ __forceinline__ bf16_t f2bf(float x) {
  unsigned u = __float_as_uint(x);
  unsigned r = (u + 0x7fffu + ((u >> 16) & 1u)) >> 16;
  unsigned short s = (unsigned short)r;
  return __builtin_bit_cast(bf16_t, s);
}

// pack two f32 -> u32 of two bf16 (round-half-up): lo16 = bf16(a), hi16 = bf16(b)
__device__ __forceinline__ unsigned pkbf(float a, float b) {
  unsigned ua = __float_as_uint(a) + 0x8000u;
  unsigned ub = __float_as_uint(b) + 0x8000u;
  return __builtin_amdgcn_perm(ub, ua, 0x07060302u);
}

// async global->LDS, 16B per lane. LDS dest must be wave-uniform base + lane*16.
__device__ __forceinline__ void gld_lds16(const bf16_t* g, bf16_t* l) {
  __builtin_amdgcn_global_load_lds(
      (const __attribute__((address_space(1))) unsigned int*)g,
      (__attribute__((address_space(3))) unsigned int*)l, 16, 0, 0);
}

// LDS row swizzle for [R][64]-bf16 tiles read as b128 columns:
// physical byte-in-row = logical byte ^ swz(row), swz(r)=((r&7)<<4)^((r&8)<<1).
// 16B-granule-preserving involution; the 16 l15-rows of a quad-group land on
// 8 distinct 16B slots (2-way = free) instead of 1 (16-way serialization).
__device__ __forceinline__ int kswz_row(int r) {
  return ((r & 7) << 4) ^ ((r & 8) << 1);
}

// ---------------- convert: x -> Xb, {Wq,Wk,Wv} -> Wqkv concat, Wo -> Wob ----
__global__ __launch_bounds__(256) void cvt_kernel(const float4* __restrict__ x,
                                                  const float4* __restrict__ wq,
                                                  const float4* __restrict__ wk,
                                                  const float4* __restrict__ wv,
                                                  const float4* __restrict__ wo,
                                                  bf16x4* __restrict__ xb,
                                                  bf16x4* __restrict__ wqkv,
                                                  bf16x4* __restrict__ wob) {
  const int NX = (2 * 2048 * 1024) / 4;  // 2,097,152
  const int NW = (1024 * 1024) / 4;      // 262,144 = 2^18
  const int TOT = NX + 4 * NW;
  for (int i = blockIdx.x * 256 + threadIdx.x; i < TOT; i += gridDim.x * 256) {
    const float4* s;
    bf16x4* d;
    if (i < NX) {
      s = x + i; d = xb + i;
    } else {
      int t = i - NX;
      int w = t >> 18;
      int o = t & (NW - 1);
      if (w == 0)      { s = wq + o; d = wqkv + o; }
      else if (w == 1) { s = wk + o; d = wqkv + NW + o; }
      else if (w == 2) { s = wv + o; d = wqkv + 2 * NW + o; }
      else             { s = wo + o; d = wob + o; }
    }
    float4 v = *s;
    bf16x4 h;
    h[0] = f2bf(v.x); h[1] = f2bf(v.y); h[2] = f2bf(v.z); h[3] = f2bf(v.w);
    *d = h;
  }
}

// ---------------- QKV GEMM: C[M,N] = A[M,K] * B[N,K]^T -----------------------
// Q,K blocks: LDS repack -> vectorized 16B stores to [b,h,s,hd] (Q pre-scaled).
// V blocks: LDS-transpose epilogue -> Vt[bh][d][s]. 128x128x64, grid (24,32).
// As/Bs staged via gld_lds16 with pre-swizzled SOURCE; fragment reads apply
// the same XOR -> 2-way banked (R11). XCD block swizzle (R12): col-major
// decode so each XCD's 96 blocks span 3 bx columns -> 3 B-panels (768KB)
// stay L2-resident.
__global__ __launch_bounds__(256) void gemm128s(const bf16_t* __restrict__ A,
                                                const bf16_t* __restrict__ B,
                                                bf16_t* __restrict__ Qo,
                                                bf16_t* __restrict__ Ko,
                                                bf16_t* __restrict__ Vt,
                                                int M, int N, int K) {
  constexpr int TS = 137;  // V-transpose stride (odd: conflict-free col reads)
  constexpr int LR = 136;  // Q/K repack stride (mult of 8: 16B-aligned b128 rows)
  __shared__ __align__(16) bf16_t Sm[128 * TS];  // 35072B; aliases As/Bs staging
  bf16_t* As = Sm;
  bf16_t* Bs = Sm + 128 * 64;
  // XCD swizzle: lin%8 = XCD id; 768 blocks = 96/XCD, col-major decode.
  const int lin = blockIdx.y * 24 + blockIdx.x;
  const int wg = (lin & 7) * 96 + (lin >> 3);
  const int m0 = (wg & 31) * 128, n0 = (wg >> 5) * 128;
  const int tid = threadIdx.x, lane = tid & 63;
  const int l15 = lane & 15, quad = lane >> 4;
  const int w = tid >> 6;
  const int wr = (w >> 1) * 64, wc = (w & 1) * 64;

  // per-lane swizzled fragment offsets (elements), constant across K-steps
  const int ksw = kswz_row(l15);
  const int kofA = ((quad * 16) ^ ksw) >> 1;       // ks=0 chunk
  const int kofB = ((64 + quad * 16) ^ ksw) >> 1;  // ks=1 chunk

  f32x4 acc[4][4];
#pragma unroll
  for (int i = 0; i < 4; i++)
#pragma unroll
    for (int j = 0; j < 4; j++) acc[i][j] = f32x4{0.f, 0.f, 0.f, 0.f};

  for (int k0 = 0; k0 < K; k0 += 64) {
    __syncthreads();
#pragma unroll
    for (int r = 0; r < 4; r++) {
      int c = r * 256 + tid;
      int row = c >> 3, cb = (c & 7) * 16;
      int lb = cb ^ kswz_row(row);  // pre-swizzled source
      gld_lds16(A + (long)(m0 + row) * K + k0 + (lb >> 1), As + row * 64 + (cb >> 1));
    }
#pragma unroll
    for (int r = 0; r < 4; r++) {
      int c = r * 256 + tid;
      int row = c >> 3, cb = (c & 7) * 16;
      int lb = cb ^ kswz_row(row);
      gld_lds16(B + (long)(n0 + row) * K + k0 + (lb >> 1), Bs + row * 64 + (cb >> 1));
    }
    __syncthreads();
#pragma unroll
    for (int ks = 0; ks < 2; ks++) {
      const int kof = ks ? kofB : kofA;
      bf16x8 af[4], bv[4];
#pragma unroll
      for (int i = 0; i < 4; i++)
        af[i] = *(const bf16x8*)(As + (wr + i * 16 + l15) * 64 + kof);
#pragma unroll
      for (int j = 0; j < 4; j++)
        bv[j] = *(const bf16x8*)(Bs + (wc + j * 16 + l15) * 64 + kof);
#pragma unroll
      for (int i = 0; i < 4; i++)
#pragma unroll
        for (int j = 0; j < 4; j++) acc[i][j] = MFMA16(af[i], bv[j], acc[i][j], 0, 0, 0);
    }
  }

  const int mat = n0 >> 10;  // block entirely within one of Q/K/V (128 | 1024)
  const int hbase = (n0 & 1023) >> 6;  // first head in this 128-col span
  const int b = m0 >> 11;              // tile never crosses batch boundary
  const int sg0 = m0 & 2047;
  __syncthreads();  // all MFMA LDS reads done before Sm reuse

  if (mat < 2) {
    // scale2 = (1/sqrt(64))*log2(e), folded into Q before its single rounding
    const float sc = (mat == 0) ? 0.18033688011112042f : 1.0f;
    bf16_t* dst = (mat == 0) ? Qo : Ko;
#pragma unroll
    for (int i = 0; i < 4; i++)
#pragma unroll
      for (int j = 0; j < 4; j++) {
        int col = wc + j * 16 + l15;
#pragma unroll
        for (int r = 0; r < 4; r++) {
          int row = wr + i * 16 + quad * 4 + r;
          Sm[row * LR + col] = f2bf(acc[i][j][r] * sc);
        }
      }
    __syncthreads();
#pragma unroll
    for (int u = 0; u < 8; u++) {
      int id = u * 256 + tid;
      int row = id >> 4, ck = id & 15;  // 16 thr per row: b128 row reads, 2-way
      int head = hbase + (ck >> 3), hd0 = (ck & 7) * 8;
      bf16x8 v = *(const bf16x8*)(Sm + row * LR + ck * 8);
      *(bf16x8*)(dst + (((long)(b * 16 + head) * 2048 + (sg0 + row)) << 6) + hd0) = v;
    }
  } else {
    // V block: transpose 128(s) x 128(c) tile through LDS, write Vt[bh][d][s]
#pragma unroll
    for (int i = 0; i < 4; i++)
#pragma unroll
      for (int j = 0; j < 4; j++) {
        int col = wc + j * 16 + l15;
#pragma unroll
        for (int r = 0; r < 4; r++) {
          int row = wr + i * 16 + quad * 4 + r;
          Sm[row * TS + col] = f2bf(acc[i][j][r]);
        }
      }
    __syncthreads();
#pragma unroll
    for (int u = 0; u < 8; u++) {
      int id = u * 256 + tid;
      int col = id >> 4, sc = id & 15;  // consecutive tid -> consecutive s-chunk
      int head = hbase + (col >> 6), hd = col & 63;
      bf16x8 v;
#pragma unroll
      for (int vv = 0; vv < 8; vv++) v[vv] = Sm[(sc * 8 + vv) * TS + col];
      *(bf16x8*)(Vt + ((long)(b * 16 + head) * 64 + hd) * 2048 + sg0 + sc * 8) = v;
    }
  }
}

// ---------------- attention unit: one 64q x (JTN*16)kv step, STATIC MAX -----
// P = exp2(S) directly (scores analytically bounded); masked -> exact 0.
// l4 accumulates P per-lane; reduced once in caller's epilogue.
// K read from LDS (linear [128][64] + XOR swizzle; koffA/koffB are the
// per-lane swizzled element offsets, constant across jt).
template <int JTN, int JM0, int PS>
__device__ __forceinline__ void attn_unit(const bf16_t* Kl, const bf16_t* Vlb,
                                          int kv0, const bf16x8* qf,
                                          int q_abs, f32x4& l4, f32x4* Oacc,
                                          int l15, int quad, int koffA, int koffB) {
  f32x4 S[JTN];
#pragma unroll
  for (int jt = 0; jt < JTN; jt++) {
    const bf16_t* kr = Kl + (jt * 16 + l15) * 64;
    bf16x8 ka = *(const bf16x8*)(kr + koffA);
    bf16x8 kb = *(const bf16x8*)(kr + koffB);
    f32x4 s = f32x4{0.f, 0.f, 0.f, 0.f};
    s = MFMA16(ka, qf[0], s, 0, 0, 0);
    s = MFMA16(kb, qf[1], s, 0, 0, 0);
    S[jt] = s;
  }
#pragma unroll
  for (int jt = JM0; jt < JTN; jt++) {
    int kvb = kv0 + jt * 16 + quad * 4;
#pragma unroll
    for (int r = 0; r < 4; r++)
      if (kvb + r > q_abs) S[jt][r] = -1e30f;
  }
#pragma unroll
  for (int jt = 0; jt < JTN; jt++) {
#pragma unroll
    for (int r = 0; r < 4; r++) S[jt][r] = exp2f(S[jt][r]);
    l4 += S[jt];
  }
#pragma unroll
  for (int jt = 0; jt < JTN; jt++) {
    int2 pk;
    pk.x = (int)pkbf(S[jt][0], S[jt][1]);
    pk.y = (int)pkbf(S[jt][2], S[jt][3]);
    s16x4 pb = __builtin_bit_cast(s16x4, pk);
#pragma unroll
    for (int n = 0; n < 4; n++) {
      s16x4 av = *(const s16x4*)(Vlb + (n * 16 + l15) * PS + jt * 16 + quad * 4);
      Oacc[n] = MFMA16K16(av, pb, Oacc[n], 0, 0, 0);
    }
  }
}

// ---------------- flash attention, K dbuf + V single-buf, static-max --------
// Q(pre-scaled),K: [32][2048][64]; Vt: [32][64][2048]; O: [4096][1024].
// grid (8, 128); block 256 (4 waves, wave w owns q rows w*16..w*16+15).
//   x = blockIdx.x = XCD id; g = y&3; bh = g*8 + x -> head pinned to one XCD
//   (Q+K+V working set 3MB < 4MB L2). qt = 31-(y>>2): longest-first (LPT).
// R12: V SINGLE-buffered (padded, reg-staged) + K double-buffered (async gld,
// XOR-swizzled source): 49KB LDS -> 3 blocks/CU (12 waves, was 8).
// Two barriers/tile: barA (K drained + V ready) ... unit ... barB (PV reads
// done) -> ds_write V(next). K-prefetch gld issued right after barA drains
// for free at barB (had the whole unit to complete).
__global__ __launch_bounds__(256) void attn15b(const bf16_t* __restrict__ Q,
                                               const bf16_t* __restrict__ Kp,
                                               const bf16_t* __restrict__ Vt,
                                               bf16_t* __restrict__ O) {
  constexpr int PS = 136;
  __shared__ __align__(16) bf16_t Vl[64 * PS];      // 17408B (single buffer)
  __shared__ __align__(16) bf16_t Kl[2][128 * 64];  // 32768B
  const int g = blockIdx.y & 3, qt = 31 - (blockIdx.y >> 2);
  const int bh = g * 8 + blockIdx.x;
  const int q0 = qt * 64;
  const int nkt = (qt >> 1) + 1;
  const int tid = threadIdx.x, lane = tid & 63;
  const int l15 = lane & 15, quad = lane >> 4;
  const int w = tid >> 6;
  const bf16_t* Qb = Q + (long)bh * 2048 * 64;
  const bf16_t* Kb = Kp + (long)bh * 2048 * 64;
  const bf16_t* Vg = Vt + (long)bh * 64 * 2048;
  const int bb = bh >> 4, hh = bh & 15;

  // per-lane swizzled K read offsets (elements), constant across tiles/jt
  const int ksw = kswz_row(l15);
  const int koffA = ((quad * 16) ^ ksw) >> 1;
  const int koffB = ((quad * 16 + 64) ^ ksw) >> 1;

  bf16x8 qf[2];
#pragma unroll
  for (int ks = 0; ks < 2; ks++)
    qf[ks] = *(const bf16x8*)(Qb + (long)(q0 + w * 16 + l15) * 64 + ks * 32 + quad * 8);

  f32x4 Oacc[4];
#pragma unroll
  for (int n = 0; n < 4; n++) Oacc[n] = f32x4{0.f, 0.f, 0.f, 0.f};
  f32x4 l4 = f32x4{0.f, 0.f, 0.f, 0.f};
  const int q_abs = q0 + w * 16 + l15;

  // ---- prologue: stage K tile 0 (async gld) + V tile 0 (regs -> LDS) ----
#pragma unroll
  for (int u = 0; u < 4; u++) {
    int id = u * 256 + tid;
    int row = id >> 3, cb = (id & 7) * 16;          // LDS: linear 16B chunks
    int lb = cb ^ kswz_row(row);                    // pre-swizzled source
    gld_lds16(Kb + (long)row * 64 + (lb >> 1), &Kl[0][row * 64 + (cb >> 1)]);
  }
  bf16x8 vr[4];
#pragma unroll
  for (int r = 0; r < 4; r++) {
    int c = r * 256 + tid;
    vr[r] = *(const bf16x8*)(Vg + (long)(c >> 4) * 2048 + (c & 15) * 8);
  }
#pragma unroll
  for (int r = 0; r < 4; r++) {
    int c = r * 256 + tid;
    *(bf16x8*)(&Vl[(c >> 4) * PS + (c & 15) * 8]) = vr[r];
  }

  for (int kt = 0; kt < nkt - 1; kt++) {  // full (unmasked) tiles
    __syncthreads();  // barA: Kl[kt&1] drained (vmcnt0), Vl = V[kt] published
    const int kvn = (kt + 1) * 128;
    // async K prefetch -> Kl[(kt+1)&1]
#pragma unroll
    for (int u = 0; u < 4; u++) {
      int id = u * 256 + tid;
      int row = id >> 3, cb = (id & 7) * 16;
      int lb = cb ^ kswz_row(row);
      gld_lds16(Kb + (long)(kvn + row) * 64 + (lb >> 1),
                &Kl[(kt + 1) & 1][row * 64 + (cb >> 1)]);
    }
    // V register prefetch (consumed after barB)
#pragma unroll
    for (int r = 0; r < 4; r++) {
      int c = r * 256 + tid;
      vr[r] = *(const bf16x8*)(Vg + (long)(c >> 4) * 2048 + kvn + (c & 15) * 8);
    }
    attn_unit<8, 8, PS>(&Kl[kt & 1][0], Vl, kt * 128, qf, q_abs,
                        l4, Oacc, l15, quad, koffA, koffB);
    __syncthreads();  // barB: all waves' PV reads of V[kt] done
#pragma unroll
    for (int r = 0; r < 4; r++) {
      int c = r * 256 + tid;
      *(bf16x8*)(&Vl[(c >> 4) * PS + (c & 15) * 8]) = vr[r];
    }
  }

  __syncthreads();  // last K tile drained + V[last] published
  const int li = (nkt - 1) & 1;
  const int kvl = (nkt - 1) * 128;
  if (qt & 1)
    attn_unit<8, 4, PS>(&Kl[li][0], Vl, kvl, qf, q_abs, l4, Oacc,
                        l15, quad, koffA, koffB);
  else
    attn_unit<4, 0, PS>(&Kl[li][0], Vl, kvl, qf, q_abs, l4, Oacc,
                        l15, quad, koffA, koffB);

  // epilogue: reduce l once (over quad groups), then normalize + store.
  // lane holds O^T[d=n*16+quad*4+r][q=w*16+l15]
  float l = l4[0] + l4[1] + l4[2] + l4[3];
  l += __shfl_xor(l, 16, 64);
  l += __shfl_xor(l, 32, 64);
  const float inv = 1.0f / l;
  bf16_t* orow = O + ((long)bb * 2048 + q_abs) * 1024 + hh * 64;
#pragma unroll
  for (int n = 0; n < 4; n++) {
    int2 pk;
    pk.x = (int)pkbf(Oacc[n][0] * inv, Oacc[n][1] * inv);
    pk.y = (int)pkbf(Oacc[n][2] * inv, Oacc[n][3] * inv);
    *(int2*)(orow + n * 16 + quad * 4) = pk;
  }
}

// ---------------- final GEMM: C[M,N] f32 = A[M,K] bf16 * B[N,K]^T bf16 ------
// 128x64x64 tile, 4 waves row-split (32 rows each). grid (16,32) = 512.
// Swizzled fragment path (R11) + XCD block swizzle (R12).
__global__ __launch_bounds__(256) void gemm64s(const bf16_t* __restrict__ A,
                                               const bf16_t* __restrict__ B,
                                               float* __restrict__ C,
                                               int M, int N, int K) {
  __shared__ __align__(16) bf16_t As[128 * 64];
  __shared__ __align__(16) bf16_t Bs[64 * 64];
  // XCD swizzle: 512 blocks = 64/XCD, col-major decode (2 bx cols/XCD).
  const int lin = blockIdx.y * 16 + blockIdx.x;
  const int wg = (lin & 7) * 64 + (lin >> 3);
  const int m0 = (wg & 31) * 128, n0 = (wg >> 5) * 64;
  const int tid = threadIdx.x, lane = tid & 63;
  const int l15 = lane & 15, quad = lane >> 4;
  const int w = tid >> 6;

  const int ksw = kswz_row(l15);
  const int kofA = ((quad * 16) ^ ksw) >> 1;
  const int kofB = ((64 + quad * 16) ^ ksw) >> 1;

  f32x4 acc[2][4];
#pragma unroll
  for (int i = 0; i < 2; i++)
#pragma unroll
    for (int j = 0; j < 4; j++) acc[i][j] = f32x4{0.f, 0.f, 0.f, 0.f};

  for (int k0 = 0; k0 < K; k0 += 64) {
    __syncthreads();
#pragma unroll
    for (int r = 0; r < 4; r++) {
      int c = r * 256 + tid;
      int row = c >> 3, cb = (c & 7) * 16;
      int lb = cb ^ kswz_row(row);
      gld_lds16(A + (long)(m0 + row) * K + k0 + (lb >> 1), As + row * 64 + (cb >> 1));
    }
#pragma unroll
    for (int r = 0; r < 2; r++) {
      int c = r * 256 + tid;
      int row = c >> 3, cb = (c & 7) * 16;
      int lb = cb ^ kswz_row(row);
      gld_lds16(B + (long)(n0 + row) * K + k0 + (lb >> 1), Bs + row * 64 + (cb >> 1));
    }
    __syncthreads();
#pragma unroll
    for (int ks = 0; ks < 2; ks++) {
      const int kof = ks ? kofB : kofA;
      bf16x8 af[2], bv[4];
#pragma unroll
      for (int i = 0; i < 2; i++)
        af[i] = *(const bf16x8*)(As + (w * 32 + i * 16 + l15) * 64 + kof);
#pragma unroll
      for (int j = 0; j < 4; j++)
        bv[j] = *(const bf16x8*)(Bs + (j * 16 + l15) * 64 + kof);
#pragma unroll
      for (int i = 0; i < 2; i++)
#pragma unroll
        for (int j = 0; j < 4; j++) acc[i][j] = MFMA16(af[i], bv[j], acc[i][j], 0, 0, 0);
    }
  }

#pragma unroll
  for (int i = 0; i < 2; i++)
#pragma unroll
    for (int j = 0; j < 4; j++) {
      int col = n0 + j * 16 + l15;
#pragma unroll
      for (int r = 0; r < 4; r++) {
        int row = m0 + w * 32 + i * 16 + quad * 4 + r;
        C[(long)row * N + col] = acc[i][j][r];
      }
    }
}

// ============================================================================
extern "C" void kernel_launch(void* const* d_in, const int* in_sizes, int n_in,
                              void* d_out, int out_size, void* d_ws, size_t ws_size,
                              hipStream_t stream) {
  const float* x = (const float*)d_in[0];
  const float* Wq = (const float*)d_in[1];
  const float* Wk = (const float*)d_in[2];
  const float* Wv = (const float*)d_in[3];
  const float* Wo = (const float*)d_in[4];
  float* out = (float*)d_out;

  const long M4 = 4L * 1024 * 1024;  // 4M bf16 elems = 8MB
  dim3 blk(256);

  bf16_t* Qb = (bf16_t*)d_ws;      // [32][2048][64] (pre-scaled)
  bf16_t* Kb = Qb + M4;            // [32][2048][64]
  bf16_t* Ob = Kb + M4;            // [4096][1024] (attn output)
  bf16_t* Vtg = Ob + M4;           // [32][64][2048] (V transposed, from gemm128s)
  bf16_t* Xb = Vtg + M4;           // [4096][1024]
  bf16_t* Wqkv = Xb + M4;          // [3072][1024]
  bf16_t* Wob = Wqkv + 3L * 1024 * 1024;  // [1024][1024]

  cvt_kernel<<<4096, blk, 0, stream>>>((const float4*)x, (const float4*)Wq,
                                       (const float4*)Wk, (const float4*)Wv,
                                       (const float4*)Wo, (bf16x4*)Xb,
                                       (bf16x4*)Wqkv, (bf16x4*)Wob);
  gemm128s<<<dim3(24, 32), blk, 0, stream>>>(Xb, Wqkv, Qb, Kb, Vtg, 4096, 3072, 1024);
  attn15b<<<dim3(8, 128), blk, 0, stream>>>(Qb, Kb, Vtg, Ob);
  gemm64s<<<dim3(16, 32), blk, 0, stream>>>(Ob, Wob, out, 4096, 1024, 1024);
}

// Round 13
// 182.268 us; speedup vs baseline: 1.0404x; 1.0404x over previous
//
#include <hip/hip_runtime.h>

// MHA forward. Inputs/output f32; internal bf16 MFMA pipeline.
// b=2, s=2048, d_model=1024, heads=16, head_dim=64.
// cvt (f32->bf16) -> fused QKV gemm128s (128x128x64, As/Bs XOR-swizzled
// fragment path (R11); NATURAL block order -- gridDim.x=24 is a multiple of
// 8 so XCD = bx%8 already: each XCD keeps exactly 3 B-panels L2-resident.
// R12's col-major XCD swizzle made each XCD stream ALL of A (8MB > 4MB L2):
// FETCH 40->68.7MB, +4us. DO NOT re-swizzle grids whose x-dim % 8 == 0) ->
// attn15b (K shared via LDS w/ XOR swizzle + async gld dbuf; V reg-prefetch
// -> SINGLE padded LDS buffer w/ 2 barriers/tile: 49KB LDS -> 3 blocks/CU;
// static-max softmax; longest-first dispatch) ->
// gemm64s (swizzled frag path; natural block order, 16%8==0; O x Wo^T).
// HISTORY: attn8/attn10/attn14 spilled when register demand rose -> ONE unit
// instantiation, ONE accumulator bank, NO min-wave launch_bounds. attn13:
// per-lane V gather from L2 = 3x regression (K/V must be LDS-shared).
// attn9/12: occupancy/balance levers exhausted; only BYTES+CONFLICTS+WAVES.
// V cannot use global_load_lds: any 16B-granule swizzle either collides with
// the jt read bits or degrades to 4-way -- padded reg-staged V is optimal.

typedef __bf16 bf16_t;
typedef __attribute__((ext_vector_type(8))) __bf16 bf16x8;
typedef __attribute__((ext_vector_type(4))) __bf16 bf16x4;
typedef __attribute__((ext_vector_type(4))) short s16x4;
typedef __attribute__((ext_vector_type(4))) float f32x4;

#define MFMA16 __builtin_amdgcn_mfma_f32_16x16x32_bf16
#define MFMA16K16 __builtin_amdgcn_mfma_f32_16x16x16bf16_1k

__device__ __forceinline__ bf16_t f2bf(float x) {
  unsigned u = __float_as_uint(x);
  unsigned r = (u + 0x7fffu + ((u >> 16) & 1u)) >> 16;
  unsigned short s = (unsigned short)r;
  return __builtin_bit_cast(bf16_t, s);
}

// pack two f32 -> u32 of two bf16 (round-half-up): lo16 = bf16(a), hi16 = bf16(b)
__device__ __forceinline__ unsigned pkbf(float a, float b) {
  unsigned ua = __float_as_uint(a) + 0x8000u;
  unsigned ub = __float_as_uint(b) + 0x8000u;
  return __builtin_amdgcn_perm(ub, ua, 0x07060302u);
}

// async global->LDS, 16B per lane. LDS dest must be wave-uniform base + lane*16.
__device__ __forceinline__ void gld_lds16(const bf16_t* g, bf16_t* l) {
  __builtin_amdgcn_global_load_lds(
      (const __attribute__((address_space(1))) unsigned int*)g,
      (__attribute__((address_space(3))) unsigned int*)l, 16, 0, 0);
}

// LDS row swizzle for [R][64]-bf16 tiles read as b128 columns:
// physical byte-in-row = logical byte ^ swz(row), swz(r)=((r&7)<<4)^((r&8)<<1).
// 16B-granule-preserving involution; the 16 l15-rows of a quad-group land on
// 8 distinct 16B slots (2-way = free) instead of 1 (16-way serialization).
__device__ __forceinline__ int kswz_row(int r) {
  return ((r & 7) << 4) ^ ((r & 8) << 1);
}

// ---------------- convert: x -> Xb, {Wq,Wk,Wv} -> Wqkv concat, Wo -> Wob ----
__global__ __launch_bounds__(256) void cvt_kernel(const float4* __restrict__ x,
                                                  const float4* __restrict__ wq,
                                                  const float4* __restrict__ wk,
                                                  const float4* __restrict__ wv,
                                                  const float4* __restrict__ wo,
                                                  bf16x4* __restrict__ xb,
                                                  bf16x4* __restrict__ wqkv,
                                                  bf16x4* __restrict__ wob) {
  const int NX = (2 * 2048 * 1024) / 4;  // 2,097,152
  const int NW = (1024 * 1024) / 4;      // 262,144 = 2^18
  const int TOT = NX + 4 * NW;
  for (int i = blockIdx.x * 256 + threadIdx.x; i < TOT; i += gridDim.x * 256) {
    const float4* s;
    bf16x4* d;
    if (i < NX) {
      s = x + i; d = xb + i;
    } else {
      int t = i - NX;
      int w = t >> 18;
      int o = t & (NW - 1);
      if (w == 0)      { s = wq + o; d = wqkv + o; }
      else if (w == 1) { s = wk + o; d = wqkv + NW + o; }
      else if (w == 2) { s = wv + o; d = wqkv + 2 * NW + o; }
      else             { s = wo + o; d = wob + o; }
    }
    float4 v = *s;
    bf16x4 h;
    h[0] = f2bf(v.x); h[1] = f2bf(v.y); h[2] = f2bf(v.z); h[3] = f2bf(v.w);
    *d = h;
  }
}

// ---------------- QKV GEMM: C[M,N] = A[M,K] * B[N,K]^T -----------------------
// Q,K blocks: LDS repack -> vectorized 16B stores to [b,h,s,hd] (Q pre-scaled).
// V blocks: LDS-transpose epilogue -> Vt[bh][d][s]. 128x128x64, grid (24,32).
// As/Bs staged via gld_lds16 with pre-swizzled SOURCE; fragment reads apply
// the same XOR -> 2-way banked (R11). NATURAL block order: 24%8==0 so
// XCD = bx%8; each XCD keeps 3 B-panels (768KB) L2-resident (R12 lesson).
__global__ __launch_bounds__(256) void gemm128s(const bf16_t* __restrict__ A,
                                                const bf16_t* __restrict__ B,
                                                bf16_t* __restrict__ Qo,
                                                bf16_t* __restrict__ Ko,
                                                bf16_t* __restrict__ Vt,
                                                int M, int N, int K) {
  constexpr int TS = 137;  // V-transpose stride (odd: conflict-free col reads)
  constexpr int LR = 136;  // Q/K repack stride (mult of 8: 16B-aligned b128 rows)
  __shared__ __align__(16) bf16_t Sm[128 * TS];  // 35072B; aliases As/Bs staging
  bf16_t* As = Sm;
  bf16_t* Bs = Sm + 128 * 64;
  const int m0 = blockIdx.y * 128, n0 = blockIdx.x * 128;
  const int tid = threadIdx.x, lane = tid & 63;
  const int l15 = lane & 15, quad = lane >> 4;
  const int w = tid >> 6;
  const int wr = (w >> 1) * 64, wc = (w & 1) * 64;

  // per-lane swizzled fragment offsets (elements), constant across K-steps
  const int ksw = kswz_row(l15);
  const int kofA = ((quad * 16) ^ ksw) >> 1;       // ks=0 chunk
  const int kofB = ((64 + quad * 16) ^ ksw) >> 1;  // ks=1 chunk

  f32x4 acc[4][4];
#pragma unroll
  for (int i = 0; i < 4; i++)
#pragma unroll
    for (int j = 0; j < 4; j++) acc[i][j] = f32x4{0.f, 0.f, 0.f, 0.f};

  for (int k0 = 0; k0 < K; k0 += 64) {
    __syncthreads();
#pragma unroll
    for (int r = 0; r < 4; r++) {
      int c = r * 256 + tid;
      int row = c >> 3, cb = (c & 7) * 16;
      int lb = cb ^ kswz_row(row);  // pre-swizzled source
      gld_lds16(A + (long)(m0 + row) * K + k0 + (lb >> 1), As + row * 64 + (cb >> 1));
    }
#pragma unroll
    for (int r = 0; r < 4; r++) {
      int c = r * 256 + tid;
      int row = c >> 3, cb = (c & 7) * 16;
      int lb = cb ^ kswz_row(row);
      gld_lds16(B + (long)(n0 + row) * K + k0 + (lb >> 1), Bs + row * 64 + (cb >> 1));
    }
    __syncthreads();
#pragma unroll
    for (int ks = 0; ks < 2; ks++) {
      const int kof = ks ? kofB : kofA;
      bf16x8 af[4], bv[4];
#pragma unroll
      for (int i = 0; i < 4; i++)
        af[i] = *(const bf16x8*)(As + (wr + i * 16 + l15) * 64 + kof);
#pragma unroll
      for (int j = 0; j < 4; j++)
        bv[j] = *(const bf16x8*)(Bs + (wc + j * 16 + l15) * 64 + kof);
#pragma unroll
      for (int i = 0; i < 4; i++)
#pragma unroll
        for (int j = 0; j < 4; j++) acc[i][j] = MFMA16(af[i], bv[j], acc[i][j], 0, 0, 0);
    }
  }

  const int mat = n0 >> 10;  // block entirely within one of Q/K/V (128 | 1024)
  const int hbase = (n0 & 1023) >> 6;  // first head in this 128-col span
  const int b = m0 >> 11;              // tile never crosses batch boundary
  const int sg0 = m0 & 2047;
  __syncthreads();  // all MFMA LDS reads done before Sm reuse

  if (mat < 2) {
    // scale2 = (1/sqrt(64))*log2(e), folded into Q before its single rounding
    const float sc = (mat == 0) ? 0.18033688011112042f : 1.0f;
    bf16_t* dst = (mat == 0) ? Qo : Ko;
#pragma unroll
    for (int i = 0; i < 4; i++)
#pragma unroll
      for (int j = 0; j < 4; j++) {
        int col = wc + j * 16 + l15;
#pragma unroll
        for (int r = 0; r < 4; r++) {
          int row = wr + i * 16 + quad * 4 + r;
          Sm[row * LR + col] = f2bf(acc[i][j][r] * sc);
        }
      }
    __syncthreads();
#pragma unroll
    for (int u = 0; u < 8; u++) {
      int id = u * 256 + tid;
      int row = id >> 4, ck = id & 15;  // 16 thr per row: b128 row reads, 2-way
      int head = hbase + (ck >> 3), hd0 = (ck & 7) * 8;
      bf16x8 v = *(const bf16x8*)(Sm + row * LR + ck * 8);
      *(bf16x8*)(dst + (((long)(b * 16 + head) * 2048 + (sg0 + row)) << 6) + hd0) = v;
    }
  } else {
    // V block: transpose 128(s) x 128(c) tile through LDS, write Vt[bh][d][s]
#pragma unroll
    for (int i = 0; i < 4; i++)
#pragma unroll
      for (int j = 0; j < 4; j++) {
        int col = wc + j * 16 + l15;
#pragma unroll
        for (int r = 0; r < 4; r++) {
          int row = wr + i * 16 + quad * 4 + r;
          Sm[row * TS + col] = f2bf(acc[i][j][r]);
        }
      }
    __syncthreads();
#pragma unroll
    for (int u = 0; u < 8; u++) {
      int id = u * 256 + tid;
      int col = id >> 4, sc = id & 15;  // consecutive tid -> consecutive s-chunk
      int head = hbase + (col >> 6), hd = col & 63;
      bf16x8 v;
#pragma unroll
      for (int vv = 0; vv < 8; vv++) v[vv] = Sm[(sc * 8 + vv) * TS + col];
      *(bf16x8*)(Vt + ((long)(b * 16 + head) * 64 + hd) * 2048 + sg0 + sc * 8) = v;
    }
  }
}

// ---------------- attention unit: one 64q x (JTN*16)kv step, STATIC MAX -----
// P = exp2(S) directly (scores analytically bounded); masked -> exact 0.
// l4 accumulates P per-lane; reduced once in caller's epilogue.
// K read from LDS (linear [128][64] + XOR swizzle; koffA/koffB are the
// per-lane swizzled element offsets, constant across jt).
template <int JTN, int JM0, int PS>
__device__ __forceinline__ void attn_unit(const bf16_t* Kl, const bf16_t* Vlb,
                                          int kv0, const bf16x8* qf,
                                          int q_abs, f32x4& l4, f32x4* Oacc,
                                          int l15, int quad, int koffA, int koffB) {
  f32x4 S[JTN];
#pragma unroll
  for (int jt = 0; jt < JTN; jt++) {
    const bf16_t* kr = Kl + (jt * 16 + l15) * 64;
    bf16x8 ka = *(const bf16x8*)(kr + koffA);
    bf16x8 kb = *(const bf16x8*)(kr + koffB);
    f32x4 s = f32x4{0.f, 0.f, 0.f, 0.f};
    s = MFMA16(ka, qf[0], s, 0, 0, 0);
    s = MFMA16(kb, qf[1], s, 0, 0, 0);
    S[jt] = s;
  }
#pragma unroll
  for (int jt = JM0; jt < JTN; jt++) {
    int kvb = kv0 + jt * 16 + quad * 4;
#pragma unroll
    for (int r = 0; r < 4; r++)
      if (kvb + r > q_abs) S[jt][r] = -1e30f;
  }
#pragma unroll
  for (int jt = 0; jt < JTN; jt++) {
#pragma unroll
    for (int r = 0; r < 4; r++) S[jt][r] = exp2f(S[jt][r]);
    l4 += S[jt];
  }
#pragma unroll
  for (int jt = 0; jt < JTN; jt++) {
    int2 pk;
    pk.x = (int)pkbf(S[jt][0], S[jt][1]);
    pk.y = (int)pkbf(S[jt][2], S[jt][3]);
    s16x4 pb = __builtin_bit_cast(s16x4, pk);
#pragma unroll
    for (int n = 0; n < 4; n++) {
      s16x4 av = *(const s16x4*)(Vlb + (n * 16 + l15) * PS + jt * 16 + quad * 4);
      Oacc[n] = MFMA16K16(av, pb, Oacc[n], 0, 0, 0);
    }
  }
}

// ---------------- flash attention, K dbuf + V single-buf, static-max --------
// Q(pre-scaled),K: [32][2048][64]; Vt: [32][64][2048]; O: [4096][1024].
// grid (8, 128); block 256 (4 waves, wave w owns q rows w*16..w*16+15).
//   x = blockIdx.x = XCD id; g = y&3; bh = g*8 + x -> head pinned to one XCD
//   (Q+K+V working set 3MB < 4MB L2). qt = 31-(y>>2): longest-first (LPT).
// V SINGLE-buffered (padded, reg-staged) + K double-buffered (async gld,
// XOR-swizzled source): 49KB LDS -> 3 blocks/CU (12 waves).
// Two barriers/tile: barA (K drained + V ready) ... unit ... barB (PV reads
// done) -> ds_write V(next).
__global__ __launch_bounds__(256) void attn15b(const bf16_t* __restrict__ Q,
                                               const bf16_t* __restrict__ Kp,
                                               const bf16_t* __restrict__ Vt,
                                               bf16_t* __restrict__ O) {
  constexpr int PS = 136;
  __shared__ __align__(16) bf16_t Vl[64 * PS];      // 17408B (single buffer)
  __shared__ __align__(16) bf16_t Kl[2][128 * 64];  // 32768B
  const int g = blockIdx.y & 3, qt = 31 - (blockIdx.y >> 2);
  const int bh = g * 8 + blockIdx.x;
  const int q0 = qt * 64;
  const int nkt = (qt >> 1) + 1;
  const int tid = threadIdx.x, lane = tid & 63;
  const int l15 = lane & 15, quad = lane >> 4;
  const int w = tid >> 6;
  const bf16_t* Qb = Q + (long)bh * 2048 * 64;
  const bf16_t* Kb = Kp + (long)bh * 2048 * 64;
  const bf16_t* Vg = Vt + (long)bh * 64 * 2048;
  const int bb = bh >> 4, hh = bh & 15;

  // per-lane swizzled K read offsets (elements), constant across tiles/jt
  const int ksw = kswz_row(l15);
  const int koffA = ((quad * 16) ^ ksw) >> 1;
  const int koffB = ((quad * 16 + 64) ^ ksw) >> 1;

  bf16x8 qf[2];
#pragma unroll
  for (int ks = 0; ks < 2; ks++)
    qf[ks] = *(const bf16x8*)(Qb + (long)(q0 + w * 16 + l15) * 64 + ks * 32 + quad * 8);

  f32x4 Oacc[4];
#pragma unroll
  for (int n = 0; n < 4; n++) Oacc[n] = f32x4{0.f, 0.f, 0.f, 0.f};
  f32x4 l4 = f32x4{0.f, 0.f, 0.f, 0.f};
  const int q_abs = q0 + w * 16 + l15;

  // ---- prologue: stage K tile 0 (async gld) + V tile 0 (regs -> LDS) ----
#pragma unroll
  for (int u = 0; u < 4; u++) {
    int id = u * 256 + tid;
    int row = id >> 3, cb = (id & 7) * 16;          // LDS: linear 16B chunks
    int lb = cb ^ kswz_row(row);                    // pre-swizzled source
    gld_lds16(Kb + (long)row * 64 + (lb >> 1), &Kl[0][row * 64 + (cb >> 1)]);
  }
  bf16x8 vr[4];
#pragma unroll
  for (int r = 0; r < 4; r++) {
    int c = r * 256 + tid;
    vr[r] = *(const bf16x8*)(Vg + (long)(c >> 4) * 2048 + (c & 15) * 8);
  }
#pragma unroll
  for (int r = 0; r < 4; r++) {
    int c = r * 256 + tid;
    *(bf16x8*)(&Vl[(c >> 4) * PS + (c & 15) * 8]) = vr[r];
  }

  for (int kt = 0; kt < nkt - 1; kt++) {  // full (unmasked) tiles
    __syncthreads();  // barA: Kl[kt&1] drained (vmcnt0), Vl = V[kt] published
    const int kvn = (kt + 1) * 128;
    // async K prefetch -> Kl[(kt+1)&1]
#pragma unroll
    for (int u = 0; u < 4; u++) {
      int id = u * 256 + tid;
      int row = id >> 3, cb = (id & 7) * 16;
      int lb = cb ^ kswz_row(row);
      gld_lds16(Kb + (long)(kvn + row) * 64 + (lb >> 1),
                &Kl[(kt + 1) & 1][row * 64 + (cb >> 1)]);
    }
    // V register prefetch (consumed after barB)
#pragma unroll
    for (int r = 0; r < 4; r++) {
      int c = r * 256 + tid;
      vr[r] = *(const bf16x8*)(Vg + (long)(c >> 4) * 2048 + kvn + (c & 15) * 8);
    }
    attn_unit<8, 8, PS>(&Kl[kt & 1][0], Vl, kt * 128, qf, q_abs,
                        l4, Oacc, l15, quad, koffA, koffB);
    __syncthreads();  // barB: all waves' PV reads of V[kt] done
#pragma unroll
    for (int r = 0; r < 4; r++) {
      int c = r * 256 + tid;
      *(bf16x8*)(&Vl[(c >> 4) * PS + (c & 15) * 8]) = vr[r];
    }
  }

  __syncthreads();  // last K tile drained + V[last] published
  const int li = (nkt - 1) & 1;
  const int kvl = (nkt - 1) * 128;
  if (qt & 1)
    attn_unit<8, 4, PS>(&Kl[li][0], Vl, kvl, qf, q_abs, l4, Oacc,
                        l15, quad, koffA, koffB);
  else
    attn_unit<4, 0, PS>(&Kl[li][0], Vl, kvl, qf, q_abs, l4, Oacc,
                        l15, quad, koffA, koffB);

  // epilogue: reduce l once (over quad groups), then normalize + store.
  // lane holds O^T[d=n*16+quad*4+r][q=w*16+l15]
  float l = l4[0] + l4[1] + l4[2] + l4[3];
  l += __shfl_xor(l, 16, 64);
  l += __shfl_xor(l, 32, 64);
  const float inv = 1.0f / l;
  bf16_t* orow = O + ((long)bb * 2048 + q_abs) * 1024 + hh * 64;
#pragma unroll
  for (int n = 0; n < 4; n++) {
    int2 pk;
    pk.x = (int)pkbf(Oacc[n][0] * inv, Oacc[n][1] * inv);
    pk.y = (int)pkbf(Oacc[n][2] * inv, Oacc[n][3] * inv);
    *(int2*)(orow + n * 16 + quad * 4) = pk;
  }
}

// ---------------- final GEMM: C[M,N] f32 = A[M,K] bf16 * B[N,K]^T bf16 ------
// 128x64x64 tile, 4 waves row-split (32 rows each). grid (16,32) = 512.
// Swizzled fragment path (R11); NATURAL block order (16%8==0 -> XCD=bx%8,
// 2 B-panels resident per XCD -- R12 lesson).
__global__ __launch_bounds__(256) void gemm64s(const bf16_t* __restrict__ A,
                                               const bf16_t* __restrict__ B,
                                               float* __restrict__ C,
                                               int M, int N, int K) {
  __shared__ __align__(16) bf16_t As[128 * 64];
  __shared__ __align__(16) bf16_t Bs[64 * 64];
  const int m0 = blockIdx.y * 128, n0 = blockIdx.x * 64;
  const int tid = threadIdx.x, lane = tid & 63;
  const int l15 = lane & 15, quad = lane >> 4;
  const int w = tid >> 6;

  const int ksw = kswz_row(l15);
  const int kofA = ((quad * 16) ^ ksw) >> 1;
  const int kofB = ((64 + quad * 16) ^ ksw) >> 1;

  f32x4 acc[2][4];
#pragma unroll
  for (int i = 0; i < 2; i++)
#pragma unroll
    for (int j = 0; j < 4; j++) acc[i][j] = f32x4{0.f, 0.f, 0.f, 0.f};

  for (int k0 = 0; k0 < K; k0 += 64) {
    __syncthreads();
#pragma unroll
    for (int r = 0; r < 4; r++) {
      int c = r * 256 + tid;
      int row = c >> 3, cb = (c & 7) * 16;
      int lb = cb ^ kswz_row(row);
      gld_lds16(A + (long)(m0 + row) * K + k0 + (lb >> 1), As + row * 64 + (cb >> 1));
    }
#pragma unroll
    for (int r = 0; r < 2; r++) {
      int c = r * 256 + tid;
      int row = c >> 3, cb = (c & 7) * 16;
      int lb = cb ^ kswz_row(row);
      gld_lds16(B + (long)(n0 + row) * K + k0 + (lb >> 1), Bs + row * 64 + (cb >> 1));
    }
    __syncthreads();
#pragma unroll
    for (int ks = 0; ks < 2; ks++) {
      const int kof = ks ? kofB : kofA;
      bf16x8 af[2], bv[4];
#pragma unroll
      for (int i = 0; i < 2; i++)
        af[i] = *(const bf16x8*)(As + (w * 32 + i * 16 + l15) * 64 + kof);
#pragma unroll
      for (int j = 0; j < 4; j++)
        bv[j] = *(const bf16x8*)(Bs + (j * 16 + l15) * 64 + kof);
#pragma unroll
      for (int i = 0; i < 2; i++)
#pragma unroll
        for (int j = 0; j < 4; j++) acc[i][j] = MFMA16(af[i], bv[j], acc[i][j], 0, 0, 0);
    }
  }

#pragma unroll
  for (int i = 0; i < 2; i++)
#pragma unroll
    for (int j = 0; j < 4; j++) {
      int col = n0 + j * 16 + l15;
#pragma unroll
      for (int r = 0; r < 4; r++) {
        int row = m0 + w * 32 + i * 16 + quad * 4 + r;
        C[(long)row * N + col] = acc[i][j][r];
      }
    }
}

// ============================================================================
extern "C" void kernel_launch(void* const* d_in, const int* in_sizes, int n_in,
                              void* d_out, int out_size, void* d_ws, size_t ws_size,
                              hipStream_t stream) {
  const float* x = (const float*)d_in[0];
  const float* Wq = (const float*)d_in[1];
  const float* Wk = (const float*)d_in[2];
  const float* Wv = (const float*)d_in[3];
  const float* Wo = (const float*)d_in[4];
  float* out = (float*)d_out;

  const long M4 = 4L * 1024 * 1024;  // 4M bf16 elems = 8MB
  dim3 blk(256);

  bf16_t* Qb = (bf16_t*)d_ws;      // [32][2048][64] (pre-scaled)
  bf16_t* Kb = Qb + M4;            // [32][2048][64]
  bf16_t* Ob = Kb + M4;            // [4096][1024] (attn output)
  bf16_t* Vtg = Ob + M4;           // [32][64][2048] (V transposed, from gemm128s)
  bf16_t* Xb = Vtg + M4;           // [4096][1024]
  bf16_t* Wqkv = Xb + M4;          // [3072][1024]
  bf16_t* Wob = Wqkv + 3L * 1024 * 1024;  // [1024][1024]

  cvt_kernel<<<4096, blk, 0, stream>>>((const float4*)x, (const float4*)Wq,
                                       (const float4*)Wk, (const float4*)Wv,
                                       (const float4*)Wo, (bf16x4*)Xb,
                                       (bf16x4*)Wqkv, (bf16x4*)Wob);
  gemm128s<<<dim3(24, 32), blk, 0, stream>>>(Xb, Wqkv, Qb, Kb, Vtg, 4096, 3072, 1024);
  attn15b<<<dim3(8, 128), blk, 0, stream>>>(Qb, Kb, Vtg, Ob);
  gemm64s<<<dim3(16, 32), blk, 0, stream>>>(Ob, Wob, out, 4096, 1024, 1024);
}